// Round 8
// baseline (288.823 us; speedup 1.0000x reference)
//
#include <hip/hip_runtime.h>
#include <stdint.h>

#define DEVI __device__ __forceinline__

typedef unsigned short ushort_t;
typedef __bf16 bf16x8 __attribute__((ext_vector_type(8)));
typedef float f32x4 __attribute__((ext_vector_type(4)));
typedef unsigned short ushort8 __attribute__((ext_vector_type(8)));
typedef short s16x4 __attribute__((ext_vector_type(4)));
typedef unsigned int u32x2 __attribute__((ext_vector_type(2)));

// ---- constants ----
#define BB 4
#define TT 2048
#define CC 1024
#define NH 16
#define HD 64
#define MM (BB*TT)          // 8192

DEVI ushort_t f2bf(float f) {
    union { float f; unsigned u; } v; v.f = f;
    return (ushort_t)((v.u + 0x7FFFu + ((v.u >> 16) & 1u)) >> 16);
}

// pack two f32 into bf16x2 dword by truncation (v_perm_b32, 1 op)
DEVI unsigned pk_bf16(float lo, float hi) {
    union { float f; unsigned u; } a, b; a.f = lo; b.f = hi;
    return __builtin_amdgcn_perm(b.u, a.u, 0x07060302u);
}

typedef const __attribute__((address_space(1))) unsigned int guint_t;
typedef __attribute__((address_space(3))) unsigned int luint_t;

// async global->LDS, 16B/lane; lds dest is wave-uniform base + lane*16
DEVI void gl2lds16(const void* g, void* lds) {
    __builtin_amdgcn_global_load_lds((guint_t*)(uintptr_t)g,
                                     (luint_t*)(unsigned int)(uintptr_t)lds,
                                     16, 0, 0);
}

// ---------------- fp32 -> bf16 bulk convert (8 elems/thread) ----------------
__global__ void cvt_f32_bf16(const float* __restrict__ in,
                             ushort_t* __restrict__ out) {
    int i = blockIdx.x * 256 + threadIdx.x;
    const float4* p = (const float4*)in + (size_t)i * 2;
    float4 a = p[0], b = p[1];
    ushort8 r;
    r[0] = f2bf(a.x); r[1] = f2bf(a.y); r[2] = f2bf(a.z); r[3] = f2bf(a.w);
    r[4] = f2bf(b.x); r[5] = f2bf(b.y); r[6] = f2bf(b.z); r[7] = f2bf(b.w);
    *(ushort8*)(out + (size_t)i * 8) = r;
}

// ------------- transpose fp32 -> bf16: in[R][Cc] -> out[Cc][R] -------------
__global__ void transpose_f2b(const float* __restrict__ in,
                              ushort_t* __restrict__ out, int R, int Cc) {
    __shared__ ushort_t tile[32][33];
    int bx = blockIdx.x * 32;
    int by = blockIdx.y * 32;
    int tx = threadIdx.x & 31, ty = threadIdx.x >> 5;
    #pragma unroll
    for (int i = 0; i < 4; i++) {
        int r = ty * 4 + i;
        tile[r][tx] = f2bf(in[(size_t)(by + r) * Cc + bx + tx]);
    }
    __syncthreads();
    #pragma unroll
    for (int i = 0; i < 4; i++) {
        int r = ty * 4 + i;
        out[(size_t)(bx + r) * R + by + tx] = tile[tx][r];
    }
}

// ---------------- rope table: tab[t*32+j] = (cos, sin) ----------------
__global__ void rope_table(float2* __restrict__ tab) {
    int i = blockIdx.x * 256 + threadIdx.x;   // 65536 total
    int t = i >> 5, j = i & 31;
    float inv = exp2f((float)j * -0.41524101186092029f);
    float theta = (float)t * inv;
    float s, c;
    sincosf(theta, &s, &c);
    tab[i] = make_float2(c, s);
}

// ------- V transpose: Vb[bh][t][d] -> VbT[bh][d][t], 64x64 tiles -------
__global__ void vtrans(const ushort_t* __restrict__ Vb,
                       ushort_t* __restrict__ VbT) {
    __shared__ ushort_t tile[64 * 72];
    const int bh = blockIdx.y;
    const int t0 = blockIdx.x * 64;
    const int tid = threadIdx.x;
    const int r = tid >> 2, c = (tid & 3) * 16;
    const size_t base = (size_t)bh * (TT * HD);
    const ushort_t* g = Vb + base + (size_t)(t0 + r) * HD + c;
    *(ushort8*)&tile[r * 72 + c]     = *(const ushort8*)g;
    *(ushort8*)&tile[r * 72 + c + 8] = *(const ushort8*)(g + 8);
    __syncthreads();
    ushort8 a, b;
    #pragma unroll
    for (int j = 0; j < 8; j++) a[j] = tile[(c + j) * 72 + r];
    #pragma unroll
    for (int j = 0; j < 8; j++) b[j] = tile[(c + 8 + j) * 72 + r];
    ushort_t* o = VbT + base + (size_t)r * TT + t0 + c;
    *(ushort8*)o = a;
    *(ushort8*)(o + 8) = b;
}

// ---------------- GEMM: C = A * Bt^T  (A,Bt bf16), m97 structure ----------
// MODE 1: A=[M][Kd] row-major; qkv epilogue: rope q,k (q pre-scaled by
//         scale*log2e); scatter to [B*NH][T][HD]
// MODE 2: A head-major [(b*16+h)*2048+t][64]; fp32 store to CoutF[M][N]
template <int MODE>
__global__ __launch_bounds__(256, 2) void gemm_bt(
    const ushort_t* __restrict__ A, const ushort_t* __restrict__ Bt,
    float* __restrict__ CoutF,
    ushort_t* __restrict__ Qb, ushort_t* __restrict__ Kb, ushort_t* __restrict__ Vb,
    const float2* __restrict__ rope, int M, int N, int Kd) {
    __shared__ __attribute__((aligned(16))) ushort_t As[128 * 32];
    __shared__ __attribute__((aligned(16))) ushort_t Bs[128 * 32];

    const int tid = threadIdx.x;
    const int w = tid >> 6, l = tid & 63;
    const int lane15 = l & 15, quad = l >> 4;
    const int wm = (w >> 1) * 64, wn = (w & 1) * 64;
    const int bm = blockIdx.y, bn = blockIdx.x;

    f32x4 acc[4][4];
    #pragma unroll
    for (int i = 0; i < 4; i++)
        #pragma unroll
        for (int j = 0; j < 4; j++)
            acc[i][j] = f32x4{0.f, 0.f, 0.f, 0.f};

    const int c0 = w * 2, c1 = w * 2 + 1;
    const int lr = l >> 2, lc = (l & 3) * 8;
    const int rowA0 = bm * 128 + c0 * 16 + lr;
    const int rowA1 = bm * 128 + c1 * 16 + lr;
    const ushort_t *gA0, *gA1;
    if (MODE == 2) {
        gA0 = A + ((size_t)(rowA0 >> 11) * 32768 + (rowA0 & (TT - 1))) * HD + lc;
        gA1 = A + ((size_t)(rowA1 >> 11) * 32768 + (rowA1 & (TT - 1))) * HD + lc;
    } else {
        gA0 = A + (size_t)rowA0 * Kd + lc;
        gA1 = A + (size_t)rowA1 * Kd + lc;
    }
    const ushort_t* gB0 = Bt + (size_t)(bn * 128 + c0 * 16 + lr) * Kd + lc;
    const ushort_t* gB1 = Bt + (size_t)(bn * 128 + c1 * 16 + lr) * Kd + lc;

    for (int k0 = 0; k0 < Kd; k0 += 32) {
        size_t offA = (MODE == 2) ? ((size_t)(k0 >> 6) * 131072 + (size_t)(k0 & 63))
                                  : (size_t)k0;
        __syncthreads();   // prior iter's LDS readers done
        gl2lds16(gA0 + offA, &As[c0 * 512]);
        gl2lds16(gA1 + offA, &As[c1 * 512]);
        gl2lds16(gB0 + k0,  &Bs[c0 * 512]);
        gl2lds16(gB1 + k0,  &Bs[c1 * 512]);
        __syncthreads();   // drains vmcnt -> staged data visible

        bf16x8 af[4], bf[4];
        #pragma unroll
        for (int t = 0; t < 4; t++) {
            af[t] = *(const bf16x8*)&As[(wm + t * 16 + lane15) * 32 + quad * 8];
            bf[t] = *(const bf16x8*)&Bs[(wn + t * 16 + lane15) * 32 + quad * 8];
        }
        #pragma unroll
        for (int tm = 0; tm < 4; tm++)
            #pragma unroll
            for (int tn = 0; tn < 4; tn++)
                acc[tm][tn] = __builtin_amdgcn_mfma_f32_16x16x32_bf16(
                    af[tm], bf[tn], acc[tm][tn], 0, 0, 0);
    }

    if (MODE == 2) {
        #pragma unroll
        for (int tm = 0; tm < 4; tm++) {
            int row0 = bm * 128 + wm + tm * 16 + quad * 4;
            #pragma unroll
            for (int r = 0; r < 4; r++) {
                size_t rb = (size_t)(row0 + r) * N + bn * 128 + wn;
                #pragma unroll
                for (int tn = 0; tn < 4; tn++)
                    CoutF[rb + tn * 16 + lane15] = acc[tm][tn][r];
            }
        }
    } else {
        const float SCQ = 0.125f * 1.4426950408889634f;   // folded into Q
        const int colbase = bn * 128 + wn;          // multiple of 64
        const int seg = colbase >> 10;              // 0=q 1=k 2=v
        const int h = (colbase & 1023) >> 6;        // head
        #pragma unroll
        for (int tm = 0; tm < 4; tm++) {
            int row0 = bm * 128 + wm + tm * 16 + quad * 4;
            #pragma unroll
            for (int r = 0; r < 4; r++) {
                int row = row0 + r;
                int b = row >> 11, t = row & (TT - 1);
                size_t ob = ((size_t)(b * NH + h) * TT + t) * HD;
                if (seg == 2) {
                    #pragma unroll
                    for (int tn = 0; tn < 4; tn++)
                        Vb[ob + tn * 16 + lane15] = f2bf(acc[tm][tn][r]);
                } else {
                    ushort_t* dst = (seg == 0) ? Qb : Kb;
                    #pragma unroll
                    for (int tn = 0; tn < 2; tn++) {
                        int j = tn * 16 + lane15;       // 0..31
                        float2 cs = rope[t * 32 + j];
                        float x1 = acc[tm][tn][r];      // d = j
                        float x2 = acc[tm][tn + 2][r];  // d = j+32
                        float y1 = x1 * cs.x - x2 * cs.y;
                        float y2 = x2 * cs.x + x1 * cs.y;
                        if (seg == 0) { y1 *= SCQ; y2 *= SCQ; }
                        dst[ob + j]      = f2bf(y1);
                        dst[ob + 32 + j] = f2bf(y2);
                    }
                }
            }
        }
    }
}

// ---------------- flash attention (causal), O in place over Q --------------
// grid: (8 qt-pairs, B*NH); block 512 = 8 waves x 16 q-rows. Block handles
// q-tiles {p, 15-p} of 128 rows. BK=128 k-tiles -> (p+1)+(16-p)=17 iters per
// block, perfectly balanced. S^T = K*Q^T: S^T's C-frag (kcol=quad*4+reg,
// qrow=lane15) IS the A-operand layout of mfma_16x16x16 -> P stays in regs.
// Q pre-scaled by scale*log2e in GEMM1 (scores already in exp2 domain).
#define KS 72    // Ks row stride (elems), 16B-aligned
#define VS 136   // Vs row stride (elems), 16B-aligned
__global__ __launch_bounds__(512, 4) void attn_kernel(
    ushort_t* __restrict__ Qb, const ushort_t* __restrict__ Kb,
    const ushort_t* __restrict__ VbT) {
    __shared__ __attribute__((aligned(16))) ushort_t Ks[128 * KS];  // K [t][d]
    __shared__ __attribute__((aligned(16))) ushort_t Vs[64 * VS];   // V^T [d][t]

    const int tid = threadIdx.x;
    const int l = tid & 63;
    const int w = tid >> 6;
    const int lane15 = l & 15, quad = l >> 4;
    const int bh = blockIdx.y;
    const size_t base = (size_t)bh * (TT * HD);

    // K staging: 2x 16B per thread, rows (tid>>3) and (tid>>3)+64
    const int ksr = tid >> 3, ksd = (tid & 7) * 8;
    // V^T staging: 2x 16B per thread, rows (tid>>4) and (tid>>4)+32
    const int vsr = tid >> 4, vsd = (tid & 15) * 8;
    const ushort_t* kgb = Kb  + base + (size_t)ksr * HD + ksd;   // + kt*128*HD
    const ushort_t* vgb = VbT + base + (size_t)vsr * TT + vsd;   // + kt*128

    #pragma unroll
    for (int seg = 0; seg < 2; seg++) {
        const int qt = (seg == 0) ? (int)blockIdx.x : (15 - (int)blockIdx.x);
        const int q0 = qt * 128;
        const int rbase = q0 + w * 16;     // wave owns 16 q-rows
        const int ktmax = qt;              // BK=128 tiles

        // Q fragments (B-operand of S^T: n=lane15->qrow, k=quad*8+j->dim)
        bf16x8 qf0, qf1;
        {
            const ushort_t* qp = Qb + base + (size_t)(rbase + lane15) * HD + quad * 8;
            qf0 = *(const bf16x8*)qp;
            qf1 = *(const bf16x8*)(qp + 32);
        }

        f32x4 o[4];
        #pragma unroll
        for (int nt = 0; nt < 4; nt++) o[nt] = f32x4{0.f, 0.f, 0.f, 0.f};
        float mrow = -INFINITY, lrow = 0.f;   // per qrow=lane15

        // prefetch tile 0 of this segment
        ushort8 kr0 = *(const ushort8*)kgb;
        ushort8 kr1 = *(const ushort8*)(kgb + (size_t)64 * HD);
        ushort8 vr0 = *(const ushort8*)vgb;
        ushort8 vr1 = *(const ushort8*)(vgb + (size_t)32 * TT);

        for (int kt = 0; kt <= ktmax; kt++) {
            __syncthreads();   // prior iter's LDS readers done
            *(ushort8*)&Ks[ksr * KS + ksd]        = kr0;
            *(ushort8*)&Ks[(ksr + 64) * KS + ksd] = kr1;
            *(ushort8*)&Vs[vsr * VS + vsd]        = vr0;
            *(ushort8*)&Vs[(vsr + 32) * VS + vsd] = vr1;
            __syncthreads();
            if (kt < ktmax) {   // prefetch next tile; overlaps compute
                const ushort_t* kg2 = kgb + (size_t)(kt + 1) * 128 * HD;
                const ushort_t* vg2 = vgb + (size_t)(kt + 1) * 128;
                kr0 = *(const ushort8*)kg2;
                kr1 = *(const ushort8*)(kg2 + (size_t)64 * HD);
                vr0 = *(const ushort8*)vg2;
                vr1 = *(const ushort8*)(vg2 + (size_t)32 * TT);
            }

            // S^T: D[kcol][qrow], kcol=c*16+quad*4+reg, qrow=lane15
            f32x4 s[8];
            #pragma unroll
            for (int c = 0; c < 8; c++) {
                bf16x8 k0 = *(const bf16x8*)&Ks[(c * 16 + lane15) * KS + quad * 8];
                bf16x8 k1 = *(const bf16x8*)&Ks[(c * 16 + lane15) * KS + 32 + quad * 8];
                f32x4 z = f32x4{0.f, 0.f, 0.f, 0.f};
                z = __builtin_amdgcn_mfma_f32_16x16x32_bf16(k0, qf0, z, 0, 0, 0);
                s[c] = __builtin_amdgcn_mfma_f32_16x16x32_bf16(k1, qf1, z, 0, 0, 0);
            }

            const int qrow = rbase + lane15;
            if (kt == ktmax) {   // only the final tile straddles the diagonal
                #pragma unroll
                for (int c = 0; c < 8; c++)
                    #pragma unroll
                    for (int r = 0; r < 4; r++)
                        if (kt * 128 + c * 16 + quad * 4 + r > qrow) s[c][r] = -1e9f;
            }

            // per-qrow max: in-lane tree + cross-quad (2 shuffles)
            float mt = fmaxf(fmaxf(fmaxf(s[0][0], s[0][1]), fmaxf(s[0][2], s[0][3])),
                             fmaxf(fmaxf(s[1][0], s[1][1]), fmaxf(s[1][2], s[1][3])));
            #pragma unroll
            for (int c = 2; c < 8; c++)
                mt = fmaxf(mt, fmaxf(fmaxf(s[c][0], s[c][1]), fmaxf(s[c][2], s[c][3])));
            mt = fmaxf(mt, __shfl_xor(mt, 16, 64));
            mt = fmaxf(mt, __shfl_xor(mt, 32, 64));

            float mn = fmaxf(mrow, mt);
            float alpha = __builtin_amdgcn_exp2f(mrow - mn);
            mrow = mn;

            #pragma unroll
            for (int c = 0; c < 8; c++)
                #pragma unroll
                for (int r = 0; r < 4; r++)
                    s[c][r] = __builtin_amdgcn_exp2f(s[c][r] - mn);

            float rs = 0.f;
            #pragma unroll
            for (int c = 0; c < 8; c++)
                rs += (s[c][0] + s[c][1]) + (s[c][2] + s[c][3]);
            rs += __shfl_xor(rs, 16, 64);
            rs += __shfl_xor(rs, 32, 64);
            lrow = lrow * alpha + rs;

            // alpha lives in lane=qrow; o rows are qrow=rbase+quad*4+r
            #pragma unroll
            for (int r = 0; r < 4; r++) {
                float aO = __shfl(alpha, quad * 4 + r, 64);
                #pragma unroll
                for (int nt = 0; nt < 4; nt++) o[nt][r] *= aO;
            }

            // P A-frags (m=lane15->qrow, k=quad*4+j->kcol) == S^T C-frag.
            // Truncating pack: 2 v_perm per 4 values (P in [0,1], eps ok).
            #pragma unroll
            for (int c = 0; c < 8; c++) {
                u32x2 pd;
                pd[0] = pk_bf16(s[c][0], s[c][1]);
                pd[1] = pk_bf16(s[c][2], s[c][3]);
                s16x4 pf = __builtin_bit_cast(s16x4, pd);
                #pragma unroll
                for (int nt = 0; nt < 4; nt++) {
                    s16x4 vf = *(const s16x4*)&Vs[(nt * 16 + lane15) * VS +
                                                  c * 16 + quad * 4];
                    o[nt] = __builtin_amdgcn_mfma_f32_16x16x16bf16_1k(
                        pf, vf, o[nt], 0, 0, 0);
                }
            }
        }

        // epilogue: O in place over this wave's Q rows (head-major)
        float linv = 1.0f / lrow;   // lane=qrow domain
        #pragma unroll
        for (int r = 0; r < 4; r++) {
            float lO = __shfl(linv, quad * 4 + r, 64);
            size_t rb = base + (size_t)(rbase + quad * 4 + r) * HD;
            #pragma unroll
            for (int nt = 0; nt < 4; nt++)
                Qb[rb + nt * 16 + lane15] = f2bf(o[nt][r] * lO);
        }
    }
}

// ---------------- launch ----------------
extern "C" void kernel_launch(void* const* d_in, const int* in_sizes, int n_in,
                              void* d_out, int out_size, void* d_ws, size_t ws_size,
                              hipStream_t stream) {
    const float* x    = (const float*)d_in[0];   // [8192][1024] fp32
    const float* wqkv = (const float*)d_in[1];   // [1024][3072] fp32
    const float* wout = (const float*)d_in[2];   // [1024][1024] fp32
    float* out = (float*)d_out;                  // [8192][1024] fp32

    // ws layout (72.5 MiB total):
    char* ws = (char*)d_ws;
    ushort_t* WqkvT = (ushort_t*)(ws);                        // [3072][1024] bf16
    ushort_t* WoutT = (ushort_t*)(ws + 6291456);              // [1024][1024] bf16
    float2*   rope  = (float2*)  (ws + 8388608);              // [2048*32]
    ushort_t* Xb    = (ushort_t*)(ws + 8912896);              // [8192][1024] bf16
    ushort_t* Qb    = (ushort_t*)(ws + 8912896 + 16777216);   // [64][2048][64]
    ushort_t* Kb    = (ushort_t*)(ws + 8912896 + 2 * 16777216);
    ushort_t* Vb    = (ushort_t*)(ws + 8912896 + 3 * 16777216);
    // VbT aliases Xb: Xb is dead after GEMM1, VbT produced after GEMM1.
    ushort_t* VbT   = Xb;                                     // [64][64][2048]

    cvt_f32_bf16<<<dim3(MM * CC / (256 * 8)), 256, 0, stream>>>(x, Xb);
    transpose_f2b<<<dim3(3 * CC / 32, CC / 32), 256, 0, stream>>>(wqkv, WqkvT, CC, 3 * CC);
    transpose_f2b<<<dim3(CC / 32, CC / 32), 256, 0, stream>>>(wout, WoutT, CC, CC);
    rope_table<<<dim3(256), 256, 0, stream>>>(rope);

    gemm_bt<1><<<dim3(3 * CC / 128, MM / 128), 256, 0, stream>>>(
        Xb, WqkvT, nullptr, Qb, Kb, Vb, rope, MM, 3 * CC, CC);

    vtrans<<<dim3(TT / 64, BB * NH), 256, 0, stream>>>(Vb, VbT);

    attn_kernel<<<dim3(8, BB * NH), 512, 0, stream>>>(Qb, Kb, VbT);

    gemm_bt<2><<<dim3(CC / 128, MM / 128), 256, 0, stream>>>(
        Qb, WoutT, out, nullptr, nullptr, nullptr, nullptr, MM, CC, CC);
}